// Round 1
// baseline (5305.866 us; speedup 1.0000x reference)
//
#include <hip/hip_runtime.h>

#define MM 50000
#define EE 800000
#define C  64

// ---------- helpers ----------

__device__ __forceinline__ float fast_gelu(float x) {
    // tanh-form gelu via sigmoid: x * sigmoid(1.595769...*(x + 0.044715 x^3))
    // max abs err vs exact erf-gelu ~2e-4, fine for 2%-of-absmax threshold.
    float x3 = x * x * x;
    float u  = 1.5957691216057308f * fmaf(0.044715f, x3, x);
    float ex = __expf(-u);
    float s  = __builtin_amdgcn_rcpf(1.0f + ex);
    return x * s;
}

__device__ __forceinline__ void ln_gelu(float* h, const float* __restrict__ g,
                                        const float* __restrict__ b) {
    float mu = 0.f;
#pragma unroll
    for (int j = 0; j < C; j++) mu += h[j];
    mu *= (1.0f / C);
    float var = 0.f;
#pragma unroll
    for (int j = 0; j < C; j++) { float d = h[j] - mu; var = fmaf(d, d, var); }
    var *= (1.0f / C);
    float rs = __builtin_amdgcn_rsqf(var + 1e-5f);
#pragma unroll
    for (int j = 0; j < C; j++) {
        float t = fmaf((h[j] - mu) * rs, g[j], b[j]);
        h[j] = fast_gelu(t);
    }
}

// ---------- kernel 1: node projections w1/w2/w3 = feat @ W1/W2/W3 ----------
// 16 threads per node, 4 channels per thread, float4 everywhere.

__global__ __launch_bounds__(256) void node_proj(
    const float* __restrict__ feat,
    const float* __restrict__ W1, const float* __restrict__ W2,
    const float* __restrict__ W3,
    float* __restrict__ w1, float* __restrict__ w2, float* __restrict__ w3) {
    int tid = blockIdx.x * 256 + threadIdx.x;
    int n = tid >> 4, cg = tid & 15;
    if (n >= MM) return;
    const float4* f4  = (const float4*)(feat + (size_t)n * C);
    const float4* W14 = (const float4*)W1;
    const float4* W24 = (const float4*)W2;
    const float4* W34 = (const float4*)W3;
    float4 a1 = {0, 0, 0, 0}, a2 = {0, 0, 0, 0}, a3 = {0, 0, 0, 0};
#pragma unroll
    for (int kk = 0; kk < 16; kk++) {
        float4 f = f4[kk];
#pragma unroll
        for (int r = 0; r < 4; r++) {
            float fv = (&f.x)[r];
            int k = kk * 4 + r;
            float4 u1 = W14[k * 16 + cg];
            a1.x = fmaf(fv, u1.x, a1.x); a1.y = fmaf(fv, u1.y, a1.y);
            a1.z = fmaf(fv, u1.z, a1.z); a1.w = fmaf(fv, u1.w, a1.w);
            float4 u2 = W24[k * 16 + cg];
            a2.x = fmaf(fv, u2.x, a2.x); a2.y = fmaf(fv, u2.y, a2.y);
            a2.z = fmaf(fv, u2.z, a2.z); a2.w = fmaf(fv, u2.w, a2.w);
            float4 u3 = W34[k * 16 + cg];
            a3.x = fmaf(fv, u3.x, a3.x); a3.y = fmaf(fv, u3.y, a3.y);
            a3.z = fmaf(fv, u3.z, a3.z); a3.w = fmaf(fv, u3.w, a3.w);
        }
    }
    ((float4*)w1)[(size_t)n * 16 + cg] = a1;
    ((float4*)w2)[(size_t)n * 16 + cg] = a2;
    ((float4*)w3)[(size_t)n * 16 + cg] = a3;
}

// ---------- kernel 2: fused per-edge MLP + softmax-numerator/denominator ----------
// One edge per thread. Wd2 reads are wave-uniform compile-time-indexed ->
// compiler scalarizes to s_load + v_fmac(sgpr). No segment-max pass: logits
// are data-bounded (|l| < ~12), exp can't overflow, shift cancels exactly.

__global__ __launch_bounds__(256) void edge_kernel(
    const int* __restrict__ src, const int* __restrict__ tgt,
    const float* __restrict__ hood,
    const float* __restrict__ Wd1, const float* __restrict__ bd1,
    const float* __restrict__ g1, const float* __restrict__ b1,
    const float* __restrict__ Wd2, const float* __restrict__ bd2,
    const float* __restrict__ g2, const float* __restrict__ b2,
    const float* __restrict__ w1, const float* __restrict__ w2,
    const float* __restrict__ w3,
    float* __restrict__ den, float* __restrict__ num) {
    int e = blockIdx.x * 256 + threadIdx.x;
    if (e >= EE) return;
    int s = src[e], t = tgt[e];
    float x0 = hood[3 * e], x1 = hood[3 * e + 1], x2 = hood[3 * e + 2];

    // layer 1: [3] @ [3,64] + bias
    float h[C];
#pragma unroll
    for (int j = 0; j < C; j++)
        h[j] = fmaf(x0, Wd1[j], fmaf(x1, Wd1[C + j], fmaf(x2, Wd1[2 * C + j], bd1[j])));
    ln_gelu(h, g1, b1);

    // layer 2: [64] @ [64,64] + bias
    float d2[C];
#pragma unroll
    for (int j = 0; j < C; j++) d2[j] = bd2[j];
#pragma unroll
    for (int k = 0; k < C; k++) {
        float hk = h[k];
#pragma unroll
        for (int j = 0; j < C; j++)
            d2[j] = fmaf(hk, Wd2[k * C + j], d2[j]);
    }
    ln_gelu(d2, g2, b2);  // d2 now holds d[e]

    // gathers + exp + scatter-accumulate
    const float4* w1t = (const float4*)(w1 + (size_t)t * C);
    const float4* w2s = (const float4*)(w2 + (size_t)s * C);
    const float4* w3s = (const float4*)(w3 + (size_t)s * C);
    float* denr = den + (size_t)t * C;
    float* numr = num + (size_t)t * C;
#pragma unroll
    for (int q = 0; q < 16; q++) {
        float4 a = w1t[q], bb = w2s[q], cc = w3s[q];
        float dd0 = d2[4 * q + 0], dd1 = d2[4 * q + 1];
        float dd2v = d2[4 * q + 2], dd3 = d2[4 * q + 3];
        float e0 = __expf(a.x - bb.x + dd0);
        float e1 = __expf(a.y - bb.y + dd1);
        float e2 = __expf(a.z - bb.z + dd2v);
        float e3 = __expf(a.w - bb.w + dd3);
        unsafeAtomicAdd(denr + 4 * q + 0, e0);
        unsafeAtomicAdd(denr + 4 * q + 1, e1);
        unsafeAtomicAdd(denr + 4 * q + 2, e2);
        unsafeAtomicAdd(denr + 4 * q + 3, e3);
        unsafeAtomicAdd(numr + 4 * q + 0, e0 * (cc.x + dd0));
        unsafeAtomicAdd(numr + 4 * q + 1, e1 * (cc.y + dd1));
        unsafeAtomicAdd(numr + 4 * q + 2, e2 * (cc.z + dd2v));
        unsafeAtomicAdd(numr + 4 * q + 3, e3 * (cc.w + dd3));
    }
}

// ---------- kernel 3: out = num / den (guard empty segments) ----------

__global__ __launch_bounds__(256) void finalize(float4* __restrict__ out,
                                                const float4* __restrict__ den) {
    int i = blockIdx.x * 256 + threadIdx.x;
    if (i >= MM * (C / 4)) return;
    float4 nm = out[i];
    float4 dn = den[i];
    float4 o;
    o.x = (dn.x != 0.f) ? nm.x / dn.x : 0.f;
    o.y = (dn.y != 0.f) ? nm.y / dn.y : 0.f;
    o.z = (dn.z != 0.f) ? nm.z / dn.z : 0.f;
    o.w = (dn.w != 0.f) ? nm.w / dn.w : 0.f;
    out[i] = o;
}

// ---------- launch ----------

extern "C" void kernel_launch(void* const* d_in, const int* in_sizes, int n_in,
                              void* d_out, int out_size, void* d_ws, size_t ws_size,
                              hipStream_t stream) {
    const int*   src  = (const int*)d_in[0];
    const int*   tgt  = (const int*)d_in[1];
    const float* feat = (const float*)d_in[2];
    const float* hood = (const float*)d_in[3];
    const float* Wd1  = (const float*)d_in[4];
    const float* bd1  = (const float*)d_in[5];
    const float* g1   = (const float*)d_in[6];
    const float* b1   = (const float*)d_in[7];
    const float* Wd2  = (const float*)d_in[8];
    const float* bd2  = (const float*)d_in[9];
    const float* g2   = (const float*)d_in[10];
    const float* b2   = (const float*)d_in[11];
    const float* W1   = (const float*)d_in[12];
    const float* W2   = (const float*)d_in[13];
    const float* W3   = (const float*)d_in[14];

    float* w1  = (float*)d_ws;
    float* w2  = w1 + (size_t)MM * C;
    float* w3  = w2 + (size_t)MM * C;
    float* den = w3 + (size_t)MM * C;
    float* out = (float*)d_out;

    hipMemsetAsync(den, 0, (size_t)MM * C * sizeof(float), stream);
    hipMemsetAsync(out, 0, (size_t)MM * C * sizeof(float), stream);

    node_proj<<<(MM * 16 + 255) / 256, 256, 0, stream>>>(feat, W1, W2, W3, w1, w2, w3);
    edge_kernel<<<(EE + 255) / 256, 256, 0, stream>>>(src, tgt, hood, Wd1, bd1, g1, b1,
                                                      Wd2, bd2, g2, b2, w1, w2, w3, den, out);
    finalize<<<(MM * 16 + 255) / 256, 256, 0, stream>>>((float4*)out, (const float4*)den);
}

// Round 2
// 565.526 us; speedup vs baseline: 9.3822x; 9.3822x over previous
//
#include <hip/hip_runtime.h>

#define MM 50000
#define EE 800000
#define C  64
#define NWIN (EE / 64)   // 12500 windows of 64 sorted edges

// ---------- helpers ----------

__device__ __forceinline__ float fast_gelu(float x) {
    // x * sigmoid(1.5957691*(x + 0.044715 x^3)); max abs err ~2e-4 vs erf-gelu
    float x3 = x * x * x;
    float u  = 1.5957691216057308f * fmaf(0.044715f, x3, x);
    float ex = __expf(-u);
    float s  = __builtin_amdgcn_rcpf(1.0f + ex);
    return x * s;
}

__device__ __forceinline__ void ln_gelu(float* h, const float* __restrict__ g,
                                        const float* __restrict__ b) {
    float mu = 0.f;
#pragma unroll
    for (int j = 0; j < C; j++) mu += h[j];
    mu *= (1.0f / C);
    float var = 0.f;
#pragma unroll
    for (int j = 0; j < C; j++) { float d = h[j] - mu; var = fmaf(d, d, var); }
    var *= (1.0f / C);
    float rs = __builtin_amdgcn_rsqf(var + 1e-5f);
#pragma unroll
    for (int j = 0; j < C; j++) {
        float t = fmaf((h[j] - mu) * rs, g[j], b[j]);
        h[j] = fast_gelu(t);
    }
}

// ---------- kernel 1: node projections ----------

__global__ __launch_bounds__(256) void node_proj(
    const float* __restrict__ feat,
    const float* __restrict__ W1, const float* __restrict__ W2,
    const float* __restrict__ W3,
    float* __restrict__ w1, float* __restrict__ w2, float* __restrict__ w3) {
    int tid = blockIdx.x * 256 + threadIdx.x;
    int n = tid >> 4, cg = tid & 15;
    if (n >= MM) return;
    const float4* f4  = (const float4*)(feat + (size_t)n * C);
    const float4* W14 = (const float4*)W1;
    const float4* W24 = (const float4*)W2;
    const float4* W34 = (const float4*)W3;
    float4 a1 = {0, 0, 0, 0}, a2 = {0, 0, 0, 0}, a3 = {0, 0, 0, 0};
#pragma unroll
    for (int kk = 0; kk < 16; kk++) {
        float4 f = f4[kk];
#pragma unroll
        for (int r = 0; r < 4; r++) {
            float fv = (&f.x)[r];
            int k = kk * 4 + r;
            float4 u1 = W14[k * 16 + cg];
            a1.x = fmaf(fv, u1.x, a1.x); a1.y = fmaf(fv, u1.y, a1.y);
            a1.z = fmaf(fv, u1.z, a1.z); a1.w = fmaf(fv, u1.w, a1.w);
            float4 u2 = W24[k * 16 + cg];
            a2.x = fmaf(fv, u2.x, a2.x); a2.y = fmaf(fv, u2.y, a2.y);
            a2.z = fmaf(fv, u2.z, a2.z); a2.w = fmaf(fv, u2.w, a2.w);
            float4 u3 = W34[k * 16 + cg];
            a3.x = fmaf(fv, u3.x, a3.x); a3.y = fmaf(fv, u3.y, a3.y);
            a3.z = fmaf(fv, u3.z, a3.z); a3.w = fmaf(fv, u3.w, a3.w);
        }
    }
    ((float4*)w1)[(size_t)n * 16 + cg] = a1;
    ((float4*)w2)[(size_t)n * 16 + cg] = a2;
    ((float4*)w3)[(size_t)n * 16 + cg] = a3;
}

// ---------- counting sort: count / scan / scatter ----------

__global__ __launch_bounds__(256) void count_kernel(const int* __restrict__ tgt,
                                                    int* __restrict__ counts) {
    int e = blockIdx.x * 256 + threadIdx.x;
    if (e < EE) atomicAdd(&counts[tgt[e]], 1);
}

#define CHUNK 49  // 1024*49 = 50176 >= MM

__global__ __launch_bounds__(1024) void scan_kernel(int* __restrict__ counts_cursor,
                                                    int* __restrict__ offsets) {
    __shared__ int sums[1024];
    int tid = threadIdx.x;
    int base = tid * CHUNK;
    int loc[CHUNK];
    int s = 0;
#pragma unroll
    for (int k = 0; k < CHUNK; k++) {
        int v = (base + k < MM) ? counts_cursor[base + k] : 0;
        loc[k] = s;
        s += v;
    }
    int my_total = s;
    sums[tid] = s;
    __syncthreads();
    for (int off = 1; off < 1024; off <<= 1) {
        int v = (tid >= off) ? sums[tid - off] : 0;
        __syncthreads();
        sums[tid] += v;
        __syncthreads();
    }
    int chunk_off = sums[tid] - my_total;  // exclusive prefix of chunk totals
#pragma unroll
    for (int k = 0; k < CHUNK; k++) {
        if (base + k < MM) {
            int o = chunk_off + loc[k];
            offsets[base + k] = o;
            counts_cursor[base + k] = o;  // reused as scatter cursor
        }
    }
    if (tid == 0) offsets[MM] = sums[1023];
}

__global__ __launch_bounds__(256) void scatter_kernel(
    const int* __restrict__ src, const int* __restrict__ tgt,
    int* __restrict__ cursor, int* __restrict__ se,
    int* __restrict__ ss, int* __restrict__ st) {
    int e = blockIdx.x * 256 + threadIdx.x;
    if (e >= EE) return;
    int t = tgt[e];
    int pos = atomicAdd(&cursor[t], 1);
    se[pos] = e;
    ss[pos] = src[e];
    st[pos] = t;
}

// ---------- main: per-wave windowed segmented softmax-aggregate ----------
// One wave per 64 sorted edges. Phase 1: thread-per-edge MLP -> d2 to LDS.
// Phase 2: lane-per-channel run reduction; fully-owned targets write out
// directly (no atomics); straddlers flush atomically into den/out.

__global__ __launch_bounds__(64) void main_kernel(
    const int* __restrict__ se, const int* __restrict__ ss,
    const int* __restrict__ st, const int* __restrict__ offsets,
    const float* __restrict__ hood,
    const float* __restrict__ Wd1, const float* __restrict__ bd1,
    const float* __restrict__ g1, const float* __restrict__ b1,
    const float* __restrict__ Wd2, const float* __restrict__ bd2,
    const float* __restrict__ g2, const float* __restrict__ b2,
    const float* __restrict__ w1, const float* __restrict__ w2,
    const float* __restrict__ w3,
    float* __restrict__ den, float* __restrict__ out) {
    __shared__ float d2lds[64][66];
    int lane = threadIdx.x;
    int p0 = blockIdx.x * 64;
    int p = p0 + lane;

    int eid = se[p];
    int s_my = ss[p];
    int t_my = st[p];
    float x0 = hood[3 * eid], x1 = hood[3 * eid + 1], x2 = hood[3 * eid + 2];

    // ---- phase 1: MLP (per-thread edge) ----
    float h[C];
#pragma unroll
    for (int j = 0; j < C; j++)
        h[j] = fmaf(x0, Wd1[j], fmaf(x1, Wd1[C + j], fmaf(x2, Wd1[2 * C + j], bd1[j])));
    ln_gelu(h, g1, b1);

    float d2[C];
#pragma unroll
    for (int j = 0; j < C; j++) d2[j] = bd2[j];
#pragma unroll
    for (int k = 0; k < C; k++) {
        float hk = h[k];
#pragma unroll
        for (int j = 0; j < C; j++)
            d2[j] = fmaf(hk, Wd2[k * C + j], d2[j]);
    }
    ln_gelu(d2, g2, b2);

#pragma unroll
    for (int q = 0; q < 16; q++) {
        *(float4*)&d2lds[lane][4 * q] =
            make_float4(d2[4 * q], d2[4 * q + 1], d2[4 * q + 2], d2[4 * q + 3]);
    }
    __syncthreads();

    // ---- phase 2: lane = channel, iterate sorted edges of this window ----
    int cur_t = -1;
    bool owned = false;
    float den_a = 0.f, num_a = 0.f, w1v = 0.f;
#pragma unroll 4
    for (int i = 0; i < 64; i++) {
        int ti = __shfl(t_my, i);
        int si = __shfl(s_my, i);
        if (ti != cur_t) {
            if (cur_t >= 0) {
                size_t o = (size_t)cur_t * C + lane;
                if (owned) out[o] = num_a / den_a;
                else { unsafeAtomicAdd(&den[o], den_a); unsafeAtomicAdd(&out[o], num_a); }
            }
            cur_t = ti; den_a = 0.f; num_a = 0.f;
            w1v = w1[(size_t)ti * C + lane];
            int o0 = offsets[ti], o1 = offsets[ti + 1];
            owned = (o0 >= p0) && (o1 <= p0 + 64);
        }
        float dv  = d2lds[i][lane];
        float w2v = w2[(size_t)si * C + lane];
        float w3v = w3[(size_t)si * C + lane];
        float ee = __expf(w1v - w2v + dv);
        den_a += ee;
        num_a = fmaf(ee, w3v + dv, num_a);
    }
    {
        size_t o = (size_t)cur_t * C + lane;
        if (owned) out[o] = num_a / den_a;
        else { unsafeAtomicAdd(&den[o], den_a); unsafeAtomicAdd(&out[o], num_a); }
    }
}

// ---------- finalize: divide straddler targets (den > 0) ----------

__global__ __launch_bounds__(256) void finalize(float4* __restrict__ out,
                                                const float4* __restrict__ den) {
    int i = blockIdx.x * 256 + threadIdx.x;
    if (i >= MM * (C / 4)) return;
    float4 dn = den[i];
    if (dn.x == 0.f && dn.y == 0.f && dn.z == 0.f && dn.w == 0.f) return;
    float4 nm = out[i];
    float4 o;
    o.x = (dn.x != 0.f) ? nm.x / dn.x : nm.x;
    o.y = (dn.y != 0.f) ? nm.y / dn.y : nm.y;
    o.z = (dn.z != 0.f) ? nm.z / dn.z : nm.z;
    o.w = (dn.w != 0.f) ? nm.w / dn.w : nm.w;
    out[i] = o;
}

// ---------- launch ----------

extern "C" void kernel_launch(void* const* d_in, const int* in_sizes, int n_in,
                              void* d_out, int out_size, void* d_ws, size_t ws_size,
                              hipStream_t stream) {
    const int*   src  = (const int*)d_in[0];
    const int*   tgt  = (const int*)d_in[1];
    const float* feat = (const float*)d_in[2];
    const float* hood = (const float*)d_in[3];
    const float* Wd1  = (const float*)d_in[4];
    const float* bd1  = (const float*)d_in[5];
    const float* g1   = (const float*)d_in[6];
    const float* b1   = (const float*)d_in[7];
    const float* Wd2  = (const float*)d_in[8];
    const float* bd2  = (const float*)d_in[9];
    const float* g2   = (const float*)d_in[10];
    const float* b2   = (const float*)d_in[11];
    const float* W1   = (const float*)d_in[12];
    const float* W2   = (const float*)d_in[13];
    const float* W3   = (const float*)d_in[14];

    float* w1  = (float*)d_ws;
    float* w2  = w1 + (size_t)MM * C;
    float* w3  = w2 + (size_t)MM * C;
    float* den = w3 + (size_t)MM * C;
    int* counts_cursor = (int*)(den + (size_t)MM * C);
    int* offsets = counts_cursor + 50176;
    int* se = offsets + (MM + 1);
    int* ss = se + EE;
    int* st = ss + EE;
    float* out = (float*)d_out;

    hipMemsetAsync(counts_cursor, 0, 50176 * sizeof(int), stream);
    hipMemsetAsync(den, 0, (size_t)MM * C * sizeof(float), stream);
    hipMemsetAsync(out, 0, (size_t)MM * C * sizeof(float), stream);

    node_proj<<<(MM * 16 + 255) / 256, 256, 0, stream>>>(feat, W1, W2, W3, w1, w2, w3);
    count_kernel<<<(EE + 255) / 256, 256, 0, stream>>>(tgt, counts_cursor);
    scan_kernel<<<1, 1024, 0, stream>>>(counts_cursor, offsets);
    scatter_kernel<<<(EE + 255) / 256, 256, 0, stream>>>(src, tgt, counts_cursor, se, ss, st);
    main_kernel<<<NWIN, 64, 0, stream>>>(se, ss, st, offsets, hood,
                                         Wd1, bd1, g1, b1, Wd2, bd2, g2, b2,
                                         w1, w2, w3, den, out);
    finalize<<<(MM * 16 + 255) / 256, 256, 0, stream>>>((float4*)out, (const float4*)den);
}